// Round 15
// baseline (698.943 us; speedup 1.0000x reference)
//
#include <hip/hip_runtime.h>

#define EPS 1e-5f

typedef __attribute__((ext_vector_type(8))) short bf16x8;
typedef __attribute__((ext_vector_type(4))) float f32x4;
typedef __attribute__((ext_vector_type(4))) unsigned short u16x4;

__device__ __forceinline__ unsigned short f2b(float f) {   // f32 -> bf16 RNE
    unsigned u = __float_as_uint(f);
    unsigned r = (u + 0x7fffu + ((u >> 16) & 1u)) >> 16;
    return (unsigned short)r;
}

// ---------------- graph preprocessing ----------------

__global__ void k_cnt(const int* __restrict__ col, const float* __restrict__ w,
                      int* __restrict__ counts, float* __restrict__ deg, int E) {
    int e = blockIdx.x * blockDim.x + threadIdx.x;
    if (e < E) {
        int c = col[e];
        atomicAdd(&counts[c], 1);
        atomicAdd(&deg[c], w[e]);
    }
}

__global__ void k_dinv(const float* __restrict__ deg, float* __restrict__ dinv, int N) {
    int i = blockIdx.x * blockDim.x + threadIdx.x;
    if (i < N) dinv[i] = rsqrtf(deg[i] + 1.0f);
}

// ---- 3-stage exclusive scan of counts -> starts ----
__global__ __launch_bounds__(256) void k_scanA(const int* __restrict__ counts,
                                               int* __restrict__ starts,
                                               int* __restrict__ bsum, int N) {
    __shared__ int part[256];
    int tid = threadIdx.x;
    int t = blockIdx.x * 256 + tid;
    int v = (t < N) ? counts[t] : 0;
    part[tid] = v;
    __syncthreads();
#pragma unroll
    for (int d = 1; d < 256; d <<= 1) {
        int tmp = (tid >= d) ? part[tid - d] : 0;
        __syncthreads();
        part[tid] += tmp;
        __syncthreads();
    }
    if (t < N) starts[t] = part[tid] - v;      // local exclusive
    if (tid == 255) bsum[blockIdx.x] = part[255];
}

__global__ __launch_bounds__(256) void k_scanB(const int* __restrict__ bsum,
                                               int* __restrict__ boff, int nb) {
    __shared__ int part[256];
    int tid = threadIdx.x;
    int v = (tid < nb) ? bsum[tid] : 0;
    part[tid] = v;
    __syncthreads();
#pragma unroll
    for (int d = 1; d < 256; d <<= 1) {
        int tmp = (tid >= d) ? part[tid - d] : 0;
        __syncthreads();
        part[tid] += tmp;
        __syncthreads();
    }
    if (tid < nb) boff[tid] = part[tid] - v;   // exclusive
}

__global__ __launch_bounds__(256) void k_scanC(int* __restrict__ starts,
                                               const int* __restrict__ boff, int N) {
    int t = blockIdx.x * 256 + threadIdx.x;
    if (t < N) starts[t] += boff[blockIdx.x];
}

__global__ void k_fill(const int* __restrict__ row, const int* __restrict__ col,
                       const float* __restrict__ w, const float* __restrict__ dinv,
                       const int* __restrict__ starts, int* __restrict__ cursor,
                       int* __restrict__ row_s, float* __restrict__ nrm_s, int E) {
    int e = blockIdx.x * blockDim.x + threadIdx.x;
    if (e >= E) return;
    int c = col[e];
    int r = row[e];
    int j = starts[c] + atomicAdd(&cursor[c], 1);
    row_s[j] = r;
    nrm_s[j] = dinv[r] * w[e] * dinv[c];
}

// ---------------- weight pack: W [K][M] f32 -> Wp [M][K] bf16 (transposed) ----------------
__global__ void k_packWT(const float* __restrict__ W, unsigned short* __restrict__ Wp,
                         int K, int M) {
    int t = blockIdx.x * blockDim.x + threadIdx.x;
    if (t >= K * M) return;
    int k = t / M, j = t - k * M;
    Wp[(size_t)j * K + k] = f2b(W[t]);
}

// ---------------- BN params: scale/shift from col stats ----------------
__global__ void k_bnparam(const float* __restrict__ sums, const float* __restrict__ sumsq,
                          const float* __restrict__ g, const float* __restrict__ be,
                          float* __restrict__ scale, float* __restrict__ shift, int M) {
    int f = threadIdx.x;
    if (f >= M) return;
    float invN = 1.0f / 50000.0f;
    float mean = sums[f] * invN;
    float var = sumsq[f] * invN - mean * mean;
    float s = g[f] * rsqrtf(var + EPS);
    scale[f] = s;
    shift[f] = be[f] - mean * s;
}

// ---------------- aggregation (CSR gather, f32 in + optional inline BN, bf16 out) ----------------
__global__ __launch_bounds__(256) void k_gather4s(
        const int* __restrict__ starts, const int* __restrict__ counts,
        const int* __restrict__ row_s, const float* __restrict__ nrm_s,
        const float* __restrict__ X, const float* __restrict__ dinv,
        const float* __restrict__ scale, const float* __restrict__ shift,
        unsigned short* __restrict__ OUT, int N, int k4shift, int applyRelu)
{
    int t = blockIdx.x * blockDim.x + threadIdx.x;
    int K4 = 1 << k4shift;                 // K/4
    if (t >= (N << k4shift)) return;
    int i = t >> k4shift;
    int c4 = t & (K4 - 1);
    const float4* X4 = (const float4*)X;
    float4 sc = make_float4(1.f, 1.f, 1.f, 1.f);
    float4 sh = make_float4(0.f, 0.f, 0.f, 0.f);
    if (scale) {
        sc = *(const float4*)(scale + c4 * 4);
        sh = *(const float4*)(shift + c4 * 4);
    }
    int s0 = starts[i], cnt = counts[i];
    float a0 = 0.f, a1 = 0.f, a2 = 0.f, a3 = 0.f;
    for (int j = s0; j < s0 + cnt; ++j) {
        float w = nrm_s[j];
        float4 h = X4[(size_t)row_s[j] * K4 + c4];
        float h0 = h.x * sc.x + sh.x, h1 = h.y * sc.y + sh.y;
        float h2 = h.z * sc.z + sh.z, h3 = h.w * sc.w + sh.w;
        if (applyRelu) {
            h0 = fmaxf(h0, 0.f); h1 = fmaxf(h1, 0.f);
            h2 = fmaxf(h2, 0.f); h3 = fmaxf(h3, 0.f);
        }
        a0 += w * h0; a1 += w * h1; a2 += w * h2; a3 += w * h3;
    }
    float di = dinv[i];
    float dd = di * di;
    float4 h = X4[(size_t)i * K4 + c4];
    float h0 = h.x * sc.x + sh.x, h1 = h.y * sc.y + sh.y;
    float h2 = h.z * sc.z + sh.z, h3 = h.w * sc.w + sh.w;
    if (applyRelu) {
        h0 = fmaxf(h0, 0.f); h1 = fmaxf(h1, 0.f);
        h2 = fmaxf(h2, 0.f); h3 = fmaxf(h3, 0.f);
    }
    a0 += dd * h0; a1 += dd * h1; a2 += dd * h2; a3 += dd * h3;
    u16x4 o;
    o[0] = f2b(a0); o[1] = f2b(a1); o[2] = f2b(a2); o[3] = f2b(a3);
    ((u16x4*)OUT)[t] = o;
}

// ---------------- MFMA GEMM with LDS staging ----------------
__global__ __launch_bounds__(256) void k_gemm_mfma(
        const unsigned short* __restrict__ A, const unsigned short* __restrict__ Wp,
        const float* __restrict__ bias, float* __restrict__ Y,
        int N, int K, int M, int relu)
{
    __shared__ unsigned short As[64][40];
    __shared__ unsigned short Bs[64][40];

    int tid = threadIdx.x;
    int wv = tid >> 6;
    int l = tid & 63;
    int lr = l & 15;
    int lk = l >> 4;
    int brow = blockIdx.x * 64;
    int bcol = blockIdx.y * 64;
    int nct = (M - bcol) >> 4; if (nct > 4) nct = 4;

    int sr = tid >> 2;
    int sc = (tid & 3) * 8;
    int gr_s = brow + sr;
    int gj_s = bcol + sr;

    f32x4 acc[4] = {};

    for (int k0 = 0; k0 < K; k0 += 32) {
        bf16x8 va = {};
        if (gr_s < N) va = *(const bf16x8*)(A + (size_t)gr_s * K + k0 + sc);
        *(bf16x8*)&As[sr][sc] = va;
        bf16x8 vb = {};
        if (gj_s < M) vb = *(const bf16x8*)(Wp + (size_t)gj_s * K + k0 + sc);
        *(bf16x8*)&Bs[sr][sc] = vb;
        __syncthreads();

        bf16x8 af = *(const bf16x8*)&As[wv * 16 + lr][lk * 8];
#pragma unroll
        for (int ct = 0; ct < 4; ++ct) {
            if (ct < nct) {
                bf16x8 bf = *(const bf16x8*)&Bs[ct * 16 + lr][lk * 8];
                acc[ct] = __builtin_amdgcn_mfma_f32_16x16x32_bf16(af, bf, acc[ct], 0, 0, 0);
            }
        }
        __syncthreads();
    }

    int i0 = brow + wv * 16;
#pragma unroll
    for (int ct = 0; ct < 4; ++ct) {
        if (ct >= nct) continue;
        int j = bcol + ct * 16 + lr;
        float bj = bias ? bias[j] : 0.0f;
#pragma unroll
        for (int r = 0; r < 4; ++r) {
            int gi = i0 + lk * 4 + r;
            if (gi < N) {
                float v = acc[ct][r] + bj;
                if (relu) v = fmaxf(v, 0.f);
                Y[(size_t)gi * M + j] = v;
            }
        }
    }
}

// ---------------- BN stats: vectorized column sums (float4 + LDS reduce) ----------------
// 512 blocks; thread handles float4 col-group c4, row-subset rsub (stride R).
__global__ __launch_bounds__(256) void k_colsum4(
        const float* __restrict__ Y, float* __restrict__ sums,
        float* __restrict__ sumsq, int N, int M, int m4shift)
{
    __shared__ float4 rs[256];
    __shared__ float4 rq[256];
    int tid = threadIdx.x;
    int M4 = 1 << m4shift;              // M/4: 8..64
    int c4 = tid & (M4 - 1);
    int rsub = tid >> m4shift;
    int R = 256 >> m4shift;
    int rowsPerBlock = (N + gridDim.x - 1) / gridDim.x;
    int r0 = blockIdx.x * rowsPerBlock;
    int r1 = min(N, r0 + rowsPerBlock);
    const float4* Y4 = (const float4*)Y;
    float s0 = 0.f, s1 = 0.f, s2 = 0.f, s3 = 0.f;
    float q0 = 0.f, q1 = 0.f, q2 = 0.f, q3 = 0.f;
#pragma unroll 4
    for (int i = r0 + rsub; i < r1; i += R) {
        float4 v = Y4[(size_t)i * M4 + c4];
        s0 += v.x; s1 += v.y; s2 += v.z; s3 += v.w;
        q0 += v.x * v.x; q1 += v.y * v.y; q2 += v.z * v.z; q3 += v.w * v.w;
    }
    rs[tid] = make_float4(s0, s1, s2, s3);
    rq[tid] = make_float4(q0, q1, q2, q3);
    __syncthreads();
    for (int r = R >> 1; r >= 1; r >>= 1) {
        if (rsub < r) {
            float4 a = rs[tid + r * M4];
            float4 bq = rq[tid + r * M4];
            float4 cs = rs[tid]; float4 cq = rq[tid];
            cs.x += a.x; cs.y += a.y; cs.z += a.z; cs.w += a.w;
            cq.x += bq.x; cq.y += bq.y; cq.z += bq.z; cq.w += bq.w;
            rs[tid] = cs; rq[tid] = cq;
        }
        __syncthreads();
    }
    if (rsub == 0) {
        float4 cs = rs[tid]; float4 cq = rq[tid];
        int f = c4 * 4;
        atomicAdd(&sums[f + 0], cs.x); atomicAdd(&sums[f + 1], cs.y);
        atomicAdd(&sums[f + 2], cs.z); atomicAdd(&sums[f + 3], cs.w);
        atomicAdd(&sumsq[f + 0], cq.x); atomicAdd(&sumsq[f + 1], cq.y);
        atomicAdd(&sumsq[f + 2], cq.z); atomicAdd(&sumsq[f + 3], cq.w);
    }
}

// ---------------- BN apply (layer 5 only): f32 -> bf16 ----------------
__global__ void k_bnb(const float* __restrict__ Y, const float* __restrict__ sums,
                      const float* __restrict__ sumsq, const float* __restrict__ g,
                      const float* __restrict__ be, unsigned short* __restrict__ OB,
                      int N, int M, int reluAfter) {
    int t = blockIdx.x * blockDim.x + threadIdx.x;
    int total = (N * M) >> 2;
    if (t >= total) return;
    int f4 = t << 2;
    int i = f4 / M;
    int f = f4 - i * M;
    (void)i;
    float invN = 1.0f / 50000.0f;
    float4 y = *(const float4*)(Y + f4);
    u16x4 ob;
#pragma unroll
    for (int j = 0; j < 4; ++j) {
        float mean = sums[f + j] * invN;
        float var = sumsq[f + j] * invN - mean * mean;
        float v = g[f + j] * (((const float*)&y)[j] - mean) * rsqrtf(var + EPS) + be[f + j];
        if (reluAfter) v = fmaxf(v, 0.f);
        ob[j] = f2b(v);
    }
    *(u16x4*)(OB + f4) = ob;
}

// ---------------- FC2: wave-per-node, coalesced ----------------
__global__ __launch_bounds__(256) void k_fc2w(const float* __restrict__ T,
                                              const float* __restrict__ W2,
                                              const float* __restrict__ b2,
                                              float* __restrict__ out, int N) {
    int gid = blockIdx.x * 256 + threadIdx.x;
    int node = gid >> 6;
    int lane = threadIdx.x & 63;
    if (node >= N) return;
    const float* tr = T + (size_t)node * 128;
    float acc = tr[lane] * W2[lane] + tr[lane + 64] * W2[lane + 64];
#pragma unroll
    for (int d = 32; d; d >>= 1) acc += __shfl_xor(acc, d);
    if (lane == 0) out[node] = acc + b2[0];
}

// ---------------- host ----------------

static inline size_t align256(size_t x) { return (x + 255) & ~(size_t)255; }

extern "C" void kernel_launch(void* const* d_in, const int* in_sizes, int n_in,
                              void* d_out, int out_size, void* d_ws, size_t ws_size,
                              hipStream_t stream) {
    const int F_IN = 32;
    const int N = in_sizes[0] / F_IN;   // 50000
    const int E = in_sizes[2];          // 400000

    const float* x  = (const float*)d_in[0];
    const int*   ei = (const int*)d_in[1];
    const float* ea = (const float*)d_in[2];
    const int* row = ei;
    const int* col = ei + E;

    const float* W[5]; const float* b[5]; const float* g[5]; const float* be[5];
    for (int i = 0; i < 5; ++i) {
        W[i]  = (const float*)d_in[3 + 4 * i + 0];
        b[i]  = (const float*)d_in[3 + 4 * i + 1];
        g[i]  = (const float*)d_in[3 + 4 * i + 2];
        be[i] = (const float*)d_in[3 + 4 * i + 3];
    }
    const float* fcW1 = (const float*)d_in[23];
    const float* fcb1 = (const float*)d_in[24];
    const float* fcW2 = (const float*)d_in[25];
    const float* fcb2 = (const float*)d_in[26];

    // workspace
    char* ws = (char*)d_ws;
    size_t off = 0;
    unsigned short* XB = (unsigned short*)(ws + off); off += align256((size_t)N * 256 * 2); // bf16 (FC1 input)
    unsigned short* CB = (unsigned short*)(ws + off); off += align256((size_t)N * 128 * 2); // bf16 gathered
    float* Yf   = (float*)(ws + off); off += align256((size_t)N * 256 * 4);                 // f32 GEMM out
    float* deg  = (float*)(ws + off); off += align256((size_t)N * 4);
    float* dinv = (float*)(ws + off); off += align256((size_t)N * 4);
    int* counts = (int*)(ws + off); off += align256((size_t)N * 4);
    int* starts = (int*)(ws + off); off += align256((size_t)N * 4);
    int* cursor = (int*)(ws + off); off += align256((size_t)N * 4);
    int* row_s  = (int*)(ws + off); off += align256((size_t)E * 4);
    float* nrm_s = (float*)(ws + off); off += align256((size_t)E * 4);
    float* sums  = (float*)(ws + off); off += align256(512 * 4);
    float* sumsq = sums + 256;
    int* bsum = (int*)(ws + off); off += align256(256 * 4);
    int* boff = (int*)(ws + off); off += align256(256 * 4);
    float* scale = (float*)(ws + off); off += align256(256 * 4);
    float* shift = (float*)(ws + off); off += align256(256 * 4);
    const int KW[6] = {32, 32, 64, 128, 128, 256};
    const int MW[6] = {32, 64, 128, 128, 256, 128};
    unsigned short* Wp[6];
    for (int i = 0; i < 6; ++i) { Wp[i] = (unsigned short*)(ws + off); off += align256((size_t)KW[i] * MW[i] * 2); }
    (void)ws_size;

    const int BS = 256;
    auto grid1 = [&](long long total) { return (int)((total + BS - 1) / BS); };
    const int nb = (N + 255) / 256;   // scan blocks (196)

    // --- CSR build ---
    hipMemsetAsync(deg, 0, (size_t)N * 4, stream);
    hipMemsetAsync(counts, 0, (size_t)N * 4, stream);
    hipMemsetAsync(cursor, 0, (size_t)N * 4, stream);
    k_cnt<<<grid1(E), BS, 0, stream>>>(col, ea, counts, deg, E);
    k_dinv<<<grid1(N), BS, 0, stream>>>(deg, dinv, N);
    k_scanA<<<nb, 256, 0, stream>>>(counts, starts, bsum, N);
    k_scanB<<<1, 256, 0, stream>>>(bsum, boff, nb);
    k_scanC<<<nb, 256, 0, stream>>>(starts, boff, N);
    k_fill<<<grid1(E), BS, 0, stream>>>(row, col, ea, dinv, starts, cursor, row_s, nrm_s, E);

    // --- weight packing ---
    const float* Wsrc[6] = {W[0], W[1], W[2], W[3], W[4], fcW1};
    for (int i = 0; i < 6; ++i)
        k_packWT<<<grid1((long long)KW[i] * MW[i]), BS, 0, stream>>>(Wsrc[i], Wp[i], KW[i], MW[i]);

    auto gemm = [&](const unsigned short* Ab, int l, const float* bias, float* Y, int relu) {
        dim3 grid((N + 63) / 64, (MW[l] + 63) / 64);
        k_gemm_mfma<<<grid, 256, 0, stream>>>(Ab, Wp[l], bias, Y, N, KW[l], MW[l], relu);
    };

    // --- layer: gather(prev f32, inline BN) -> CB ; gemm -> Yf ; colsum ---
    auto layer = [&](const float* Xin, int l, int bnOf, int bnRelu, int reluBefore) {
        int K = KW[l], M = MW[l];
        int k4shift = (K == 32) ? 3 : (K == 64) ? 4 : 5;
        if (bnOf >= 0)
            k_bnparam<<<1, 256, 0, stream>>>(sums, sumsq, g[bnOf], be[bnOf], scale, shift, MW[bnOf]);
        k_gather4s<<<grid1((long long)N << k4shift), BS, 0, stream>>>(
            starts, counts, row_s, nrm_s, Xin, dinv,
            bnOf >= 0 ? scale : nullptr, bnOf >= 0 ? shift : nullptr,
            CB, N, k4shift, bnRelu);
        gemm(CB, l, b[l], Yf, reluBefore);
        hipMemsetAsync(sums, 0, 512 * 4, stream);
        int m4shift = (M == 32) ? 3 : (M == 64) ? 4 : (M == 128) ? 5 : 6;
        k_colsum4<<<512, 256, 0, stream>>>(Yf, sums, sumsq, N, M, m4shift);
    };

    layer(x,  0, -1, 0, 1);   // L1: 32 -> 32, pre-BN relu
    layer(Yf, 1, 0, 0, 1);    // L2: BN(L1) inline
    layer(Yf, 2, 1, 0, 1);    // L3
    layer(Yf, 3, 2, 0, 0);    // L4: no pre-relu
    layer(Yf, 4, 3, 1, 0);    // L5: BN(L4) inline WITH relu

    // L5 BN apply -> XB (bf16), relu
    k_bnb<<<grid1((long long)N * 256 / 4), BS, 0, stream>>>(
        Yf, sums, sumsq, g[4], be[4], XB, N, 256, 1);

    // FC1: XB(bf16 Nx256) @ fcW1 + b, ReLU -> Yf (f32 Nx128)
    gemm(XB, 5, fcb1, Yf, 1);
    // FC2: wave-per-node
    k_fc2w<<<(N * 64 + 255) / 256, 256, 0, stream>>>(Yf, fcW2, fcb2, (float*)d_out, N);
}

// Round 18
// 578.379 us; speedup vs baseline: 1.2085x; 1.2085x over previous
//
#include <hip/hip_runtime.h>

#define EPS 1e-5f

typedef __attribute__((ext_vector_type(8))) short bf16x8;
typedef __attribute__((ext_vector_type(4))) float f32x4;
typedef __attribute__((ext_vector_type(4))) unsigned short u16x4;

__device__ __forceinline__ unsigned short f2b(float f) {   // f32 -> bf16 RNE
    unsigned u = __float_as_uint(f);
    unsigned r = (u + 0x7fffu + ((u >> 16) & 1u)) >> 16;
    return (unsigned short)r;
}

// ---------------- graph preprocessing ----------------

__global__ void k_cnt(const int* __restrict__ col, const float* __restrict__ w,
                      int* __restrict__ counts, float* __restrict__ deg, int E) {
    int e = blockIdx.x * blockDim.x + threadIdx.x;
    if (e < E) {
        int c = col[e];
        atomicAdd(&counts[c], 1);
        atomicAdd(&deg[c], w[e]);
    }
}

__global__ void k_dinv(const float* __restrict__ deg, float* __restrict__ dinv, int N) {
    int i = blockIdx.x * blockDim.x + threadIdx.x;
    if (i < N) dinv[i] = rsqrtf(deg[i] + 1.0f);
}

// ---- 3-stage exclusive scan of counts -> starts ----
__global__ __launch_bounds__(256) void k_scanA(const int* __restrict__ counts,
                                               int* __restrict__ starts,
                                               int* __restrict__ bsum, int N) {
    __shared__ int part[256];
    int tid = threadIdx.x;
    int t = blockIdx.x * 256 + tid;
    int v = (t < N) ? counts[t] : 0;
    part[tid] = v;
    __syncthreads();
#pragma unroll
    for (int d = 1; d < 256; d <<= 1) {
        int tmp = (tid >= d) ? part[tid - d] : 0;
        __syncthreads();
        part[tid] += tmp;
        __syncthreads();
    }
    if (t < N) starts[t] = part[tid] - v;      // local exclusive
    if (tid == 255) bsum[blockIdx.x] = part[255];
}

__global__ __launch_bounds__(256) void k_scanB(const int* __restrict__ bsum,
                                               int* __restrict__ boff, int nb) {
    __shared__ int part[256];
    int tid = threadIdx.x;
    int v = (tid < nb) ? bsum[tid] : 0;
    part[tid] = v;
    __syncthreads();
#pragma unroll
    for (int d = 1; d < 256; d <<= 1) {
        int tmp = (tid >= d) ? part[tid - d] : 0;
        __syncthreads();
        part[tid] += tmp;
        __syncthreads();
    }
    if (tid < nb) boff[tid] = part[tid] - v;   // exclusive
}

__global__ __launch_bounds__(256) void k_scanC(int* __restrict__ starts,
                                               const int* __restrict__ boff, int N) {
    int t = blockIdx.x * 256 + threadIdx.x;
    if (t < N) starts[t] += boff[blockIdx.x];
}

__global__ void k_fill(const int* __restrict__ row, const int* __restrict__ col,
                       const float* __restrict__ w, const float* __restrict__ dinv,
                       const int* __restrict__ starts, int* __restrict__ cursor,
                       int* __restrict__ row_s, float* __restrict__ nrm_s, int E) {
    int e = blockIdx.x * blockDim.x + threadIdx.x;
    if (e >= E) return;
    int c = col[e];
    int r = row[e];
    int j = starts[c] + atomicAdd(&cursor[c], 1);
    row_s[j] = r;
    nrm_s[j] = dinv[r] * w[e] * dinv[c];
}

// ---------------- weight pack: W [K][M] f32 -> Wp [M][K] bf16 (transposed) ----------------
__global__ void k_packWT(const float* __restrict__ W, unsigned short* __restrict__ Wp,
                         int K, int M) {
    int t = blockIdx.x * blockDim.x + threadIdx.x;
    if (t >= K * M) return;
    int k = t / M, j = t - k * M;
    Wp[(size_t)j * K + k] = f2b(W[t]);
}

// ---------------- BN params: scale/shift from col stats ----------------
__global__ void k_bnparam(const float* __restrict__ sums, const float* __restrict__ sumsq,
                          const float* __restrict__ g, const float* __restrict__ be,
                          float* __restrict__ scale, float* __restrict__ shift, int M) {
    int f = threadIdx.x;
    if (f >= M) return;
    float invN = 1.0f / 50000.0f;
    float mean = sums[f] * invN;
    float var = sumsq[f] * invN - mean * mean;
    float s = g[f] * rsqrtf(var + EPS);
    scale[f] = s;
    shift[f] = be[f] - mean * s;
}

// ---------------- aggregation (CSR gather, f32 in + optional inline BN, bf16 out) ----------------
__global__ __launch_bounds__(256) void k_gather4s(
        const int* __restrict__ starts, const int* __restrict__ counts,
        const int* __restrict__ row_s, const float* __restrict__ nrm_s,
        const float* __restrict__ X, const float* __restrict__ dinv,
        const float* __restrict__ scale, const float* __restrict__ shift,
        unsigned short* __restrict__ OUT, int N, int k4shift, int applyRelu)
{
    int t = blockIdx.x * blockDim.x + threadIdx.x;
    int K4 = 1 << k4shift;                 // K/4
    if (t >= (N << k4shift)) return;
    int i = t >> k4shift;
    int c4 = t & (K4 - 1);
    const float4* X4 = (const float4*)X;
    float4 sc = make_float4(1.f, 1.f, 1.f, 1.f);
    float4 sh = make_float4(0.f, 0.f, 0.f, 0.f);
    if (scale) {
        sc = *(const float4*)(scale + c4 * 4);
        sh = *(const float4*)(shift + c4 * 4);
    }
    int s0 = starts[i], cnt = counts[i];
    float a0 = 0.f, a1 = 0.f, a2 = 0.f, a3 = 0.f;
    for (int j = s0; j < s0 + cnt; ++j) {
        float w = nrm_s[j];
        float4 h = X4[(size_t)row_s[j] * K4 + c4];
        float h0 = h.x * sc.x + sh.x, h1 = h.y * sc.y + sh.y;
        float h2 = h.z * sc.z + sh.z, h3 = h.w * sc.w + sh.w;
        if (applyRelu) {
            h0 = fmaxf(h0, 0.f); h1 = fmaxf(h1, 0.f);
            h2 = fmaxf(h2, 0.f); h3 = fmaxf(h3, 0.f);
        }
        a0 += w * h0; a1 += w * h1; a2 += w * h2; a3 += w * h3;
    }
    float di = dinv[i];
    float dd = di * di;
    float4 h = X4[(size_t)i * K4 + c4];
    float h0 = h.x * sc.x + sh.x, h1 = h.y * sc.y + sh.y;
    float h2 = h.z * sc.z + sh.z, h3 = h.w * sc.w + sh.w;
    if (applyRelu) {
        h0 = fmaxf(h0, 0.f); h1 = fmaxf(h1, 0.f);
        h2 = fmaxf(h2, 0.f); h3 = fmaxf(h3, 0.f);
    }
    a0 += dd * h0; a1 += dd * h1; a2 += dd * h2; a3 += dd * h3;
    u16x4 o;
    o[0] = f2b(a0); o[1] = f2b(a1); o[2] = f2b(a2); o[3] = f2b(a3);
    ((u16x4*)OUT)[t] = o;
}

// ---------------- MFMA GEMM with LDS staging ----------------
__global__ __launch_bounds__(256) void k_gemm_mfma(
        const unsigned short* __restrict__ A, const unsigned short* __restrict__ Wp,
        const float* __restrict__ bias, float* __restrict__ Y,
        int N, int K, int M, int relu)
{
    __shared__ unsigned short As[64][40];
    __shared__ unsigned short Bs[64][40];

    int tid = threadIdx.x;
    int wv = tid >> 6;
    int l = tid & 63;
    int lr = l & 15;
    int lk = l >> 4;
    int brow = blockIdx.x * 64;
    int bcol = blockIdx.y * 64;
    int nct = (M - bcol) >> 4; if (nct > 4) nct = 4;

    int sr = tid >> 2;
    int sc = (tid & 3) * 8;
    int gr_s = brow + sr;
    int gj_s = bcol + sr;

    f32x4 acc[4] = {};

    for (int k0 = 0; k0 < K; k0 += 32) {
        bf16x8 va = {};
        if (gr_s < N) va = *(const bf16x8*)(A + (size_t)gr_s * K + k0 + sc);
        *(bf16x8*)&As[sr][sc] = va;
        bf16x8 vb = {};
        if (gj_s < M) vb = *(const bf16x8*)(Wp + (size_t)gj_s * K + k0 + sc);
        *(bf16x8*)&Bs[sr][sc] = vb;
        __syncthreads();

        bf16x8 af = *(const bf16x8*)&As[wv * 16 + lr][lk * 8];
#pragma unroll
        for (int ct = 0; ct < 4; ++ct) {
            if (ct < nct) {
                bf16x8 bf = *(const bf16x8*)&Bs[ct * 16 + lr][lk * 8];
                acc[ct] = __builtin_amdgcn_mfma_f32_16x16x32_bf16(af, bf, acc[ct], 0, 0, 0);
            }
        }
        __syncthreads();
    }

    int i0 = brow + wv * 16;
#pragma unroll
    for (int ct = 0; ct < 4; ++ct) {
        if (ct >= nct) continue;
        int j = bcol + ct * 16 + lr;
        float bj = bias ? bias[j] : 0.0f;
#pragma unroll
        for (int r = 0; r < 4; ++r) {
            int gi = i0 + lk * 4 + r;
            if (gi < N) {
                float v = acc[ct][r] + bj;
                if (relu) v = fmaxf(v, 0.f);
                Y[(size_t)gi * M + j] = v;
            }
        }
    }
}

// ---------------- BN stats pass 1: per-block partial column sums (NO atomics) ----------------
// 512 blocks; float4 loads, LDS tree over row-subsets; block writes its partials.
__global__ __launch_bounds__(256) void k_colsum4p(
        const float* __restrict__ Y, float* __restrict__ Ps, float* __restrict__ Pq,
        int N, int M, int m4shift)
{
    __shared__ float4 rs[256];
    __shared__ float4 rq[256];
    int tid = threadIdx.x;
    int M4 = 1 << m4shift;              // M/4: 8..64
    int c4 = tid & (M4 - 1);
    int rsub = tid >> m4shift;
    int R = 256 >> m4shift;
    int rowsPerBlock = (N + gridDim.x - 1) / gridDim.x;
    int r0 = blockIdx.x * rowsPerBlock;
    int r1 = min(N, r0 + rowsPerBlock);
    const float4* Y4 = (const float4*)Y;
    float s0 = 0.f, s1 = 0.f, s2 = 0.f, s3 = 0.f;
    float q0 = 0.f, q1 = 0.f, q2 = 0.f, q3 = 0.f;
#pragma unroll 4
    for (int i = r0 + rsub; i < r1; i += R) {
        float4 v = Y4[(size_t)i * M4 + c4];
        s0 += v.x; s1 += v.y; s2 += v.z; s3 += v.w;
        q0 += v.x * v.x; q1 += v.y * v.y; q2 += v.z * v.z; q3 += v.w * v.w;
    }
    rs[tid] = make_float4(s0, s1, s2, s3);
    rq[tid] = make_float4(q0, q1, q2, q3);
    __syncthreads();
    for (int r = R >> 1; r >= 1; r >>= 1) {
        if (rsub < r) {
            float4 a = rs[tid + r * M4];
            float4 bq = rq[tid + r * M4];
            float4 cs = rs[tid]; float4 cq = rq[tid];
            cs.x += a.x; cs.y += a.y; cs.z += a.z; cs.w += a.w;
            cq.x += bq.x; cq.y += bq.y; cq.z += bq.z; cq.w += bq.w;
            rs[tid] = cs; rq[tid] = cq;
        }
        __syncthreads();
    }
    if (rsub == 0) {
        int f = c4 * 4;
        *(float4*)&Ps[(size_t)blockIdx.x * 256 + f] = rs[tid];
        *(float4*)&Pq[(size_t)blockIdx.x * 256 + f] = rq[tid];
    }
}

// ---------------- BN stats pass 2: reduce partials (coalesced, no atomics) ----------------
// 2M threads: f<M -> sums[f], else sumsq[f-M]. nb partial rows, stride 256.
__global__ __launch_bounds__(256) void k_reduceP(
        const float* __restrict__ Ps, const float* __restrict__ Pq,
        float* __restrict__ sums, float* __restrict__ sumsq, int M, int nb)
{
    int t = blockIdx.x * 256 + threadIdx.x;
    if (t >= 2 * M) return;
    const float* P = (t < M) ? Ps : Pq;
    int f = (t < M) ? t : t - M;
    float s = 0.f;
#pragma unroll 8
    for (int b = 0; b < nb; ++b) s += P[(size_t)b * 256 + f];
    if (t < M) sums[f] = s; else sumsq[f] = s;
}

// ---------------- BN apply (layer 5 only): f32 -> bf16 ----------------
__global__ void k_bnb(const float* __restrict__ Y, const float* __restrict__ sums,
                      const float* __restrict__ sumsq, const float* __restrict__ g,
                      const float* __restrict__ be, unsigned short* __restrict__ OB,
                      int N, int M, int reluAfter) {
    int t = blockIdx.x * blockDim.x + threadIdx.x;
    int total = (N * M) >> 2;
    if (t >= total) return;
    int f4 = t << 2;
    int i = f4 / M;
    int f = f4 - i * M;
    (void)i;
    float invN = 1.0f / 50000.0f;
    float4 y = *(const float4*)(Y + f4);
    u16x4 ob;
#pragma unroll
    for (int j = 0; j < 4; ++j) {
        float mean = sums[f + j] * invN;
        float var = sumsq[f + j] * invN - mean * mean;
        float v = g[f + j] * (((const float*)&y)[j] - mean) * rsqrtf(var + EPS) + be[f + j];
        if (reluAfter) v = fmaxf(v, 0.f);
        ob[j] = f2b(v);
    }
    *(u16x4*)(OB + f4) = ob;
}

// ---------------- FC2: wave-per-node, coalesced ----------------
__global__ __launch_bounds__(256) void k_fc2w(const float* __restrict__ T,
                                              const float* __restrict__ W2,
                                              const float* __restrict__ b2,
                                              float* __restrict__ out, int N) {
    int gid = blockIdx.x * 256 + threadIdx.x;
    int node = gid >> 6;
    int lane = threadIdx.x & 63;
    if (node >= N) return;
    const float* tr = T + (size_t)node * 128;
    float acc = tr[lane] * W2[lane] + tr[lane + 64] * W2[lane + 64];
#pragma unroll
    for (int d = 32; d; d >>= 1) acc += __shfl_xor(acc, d);
    if (lane == 0) out[node] = acc + b2[0];
}

// ---------------- host ----------------

static inline size_t align256(size_t x) { return (x + 255) & ~(size_t)255; }

extern "C" void kernel_launch(void* const* d_in, const int* in_sizes, int n_in,
                              void* d_out, int out_size, void* d_ws, size_t ws_size,
                              hipStream_t stream) {
    const int F_IN = 32;
    const int N = in_sizes[0] / F_IN;   // 50000
    const int E = in_sizes[2];          // 400000

    const float* x  = (const float*)d_in[0];
    const int*   ei = (const int*)d_in[1];
    const float* ea = (const float*)d_in[2];
    const int* row = ei;
    const int* col = ei + E;

    const float* W[5]; const float* b[5]; const float* g[5]; const float* be[5];
    for (int i = 0; i < 5; ++i) {
        W[i]  = (const float*)d_in[3 + 4 * i + 0];
        b[i]  = (const float*)d_in[3 + 4 * i + 1];
        g[i]  = (const float*)d_in[3 + 4 * i + 2];
        be[i] = (const float*)d_in[3 + 4 * i + 3];
    }
    const float* fcW1 = (const float*)d_in[23];
    const float* fcb1 = (const float*)d_in[24];
    const float* fcW2 = (const float*)d_in[25];
    const float* fcb2 = (const float*)d_in[26];

    // workspace
    char* ws = (char*)d_ws;
    size_t off = 0;
    unsigned short* XB = (unsigned short*)(ws + off); off += align256((size_t)N * 256 * 2); // bf16 (FC1 input)
    unsigned short* CB = (unsigned short*)(ws + off); off += align256((size_t)N * 128 * 2); // bf16 gathered
    float* Yf   = (float*)(ws + off); off += align256((size_t)N * 256 * 4);                 // f32 GEMM out
    float* deg  = (float*)(ws + off); off += align256((size_t)N * 4);
    float* dinv = (float*)(ws + off); off += align256((size_t)N * 4);
    int* counts = (int*)(ws + off); off += align256((size_t)N * 4);
    int* starts = (int*)(ws + off); off += align256((size_t)N * 4);
    int* cursor = (int*)(ws + off); off += align256((size_t)N * 4);
    int* row_s  = (int*)(ws + off); off += align256((size_t)E * 4);
    float* nrm_s = (float*)(ws + off); off += align256((size_t)E * 4);
    float* sums  = (float*)(ws + off); off += align256(512 * 4);
    float* sumsq = sums + 256;
    int* bsum = (int*)(ws + off); off += align256(256 * 4);
    int* boff = (int*)(ws + off); off += align256(256 * 4);
    float* scale = (float*)(ws + off); off += align256(256 * 4);
    float* shift = (float*)(ws + off); off += align256(256 * 4);
    float* Ps = (float*)(ws + off); off += align256((size_t)512 * 256 * 4);   // partial sums
    float* Pq = (float*)(ws + off); off += align256((size_t)512 * 256 * 4);   // partial sumsq
    const int KW[6] = {32, 32, 64, 128, 128, 256};
    const int MW[6] = {32, 64, 128, 128, 256, 128};
    unsigned short* Wp[6];
    for (int i = 0; i < 6; ++i) { Wp[i] = (unsigned short*)(ws + off); off += align256((size_t)KW[i] * MW[i] * 2); }
    (void)ws_size;

    const int BS = 256;
    auto grid1 = [&](long long total) { return (int)((total + BS - 1) / BS); };
    const int nb = (N + 255) / 256;   // scan blocks (196)
    const int CSB = 512;              // colsum partial blocks

    // --- CSR build ---
    hipMemsetAsync(deg, 0, (size_t)N * 4, stream);
    hipMemsetAsync(counts, 0, (size_t)N * 4, stream);
    hipMemsetAsync(cursor, 0, (size_t)N * 4, stream);
    k_cnt<<<grid1(E), BS, 0, stream>>>(col, ea, counts, deg, E);
    k_dinv<<<grid1(N), BS, 0, stream>>>(deg, dinv, N);
    k_scanA<<<nb, 256, 0, stream>>>(counts, starts, bsum, N);
    k_scanB<<<1, 256, 0, stream>>>(bsum, boff, nb);
    k_scanC<<<nb, 256, 0, stream>>>(starts, boff, N);
    k_fill<<<grid1(E), BS, 0, stream>>>(row, col, ea, dinv, starts, cursor, row_s, nrm_s, E);

    // --- weight packing ---
    const float* Wsrc[6] = {W[0], W[1], W[2], W[3], W[4], fcW1};
    for (int i = 0; i < 6; ++i)
        k_packWT<<<grid1((long long)KW[i] * MW[i]), BS, 0, stream>>>(Wsrc[i], Wp[i], KW[i], MW[i]);

    auto gemm = [&](const unsigned short* Ab, int l, const float* bias, float* Y, int relu) {
        dim3 grid((N + 63) / 64, (MW[l] + 63) / 64);
        k_gemm_mfma<<<grid, 256, 0, stream>>>(Ab, Wp[l], bias, Y, N, KW[l], MW[l], relu);
    };

    // --- layer: gather(prev f32, inline BN) -> CB ; gemm -> Yf ; colsum (2-pass) ---
    auto layer = [&](const float* Xin, int l, int bnOf, int bnRelu, int reluBefore) {
        int K = KW[l], M = MW[l];
        int k4shift = (K == 32) ? 3 : (K == 64) ? 4 : 5;
        if (bnOf >= 0)
            k_bnparam<<<1, 256, 0, stream>>>(sums, sumsq, g[bnOf], be[bnOf], scale, shift, MW[bnOf]);
        k_gather4s<<<grid1((long long)N << k4shift), BS, 0, stream>>>(
            starts, counts, row_s, nrm_s, Xin, dinv,
            bnOf >= 0 ? scale : nullptr, bnOf >= 0 ? shift : nullptr,
            CB, N, k4shift, bnRelu);
        gemm(CB, l, b[l], Yf, reluBefore);
        int m4shift = (M == 32) ? 3 : (M == 64) ? 4 : (M == 128) ? 5 : 6;
        k_colsum4p<<<CSB, 256, 0, stream>>>(Yf, Ps, Pq, N, M, m4shift);
        k_reduceP<<<(2 * M + 255) / 256, 256, 0, stream>>>(Ps, Pq, sums, sumsq, M, CSB);
    };

    layer(x,  0, -1, 0, 1);   // L1: 32 -> 32, pre-BN relu
    layer(Yf, 1, 0, 0, 1);    // L2: BN(L1) inline
    layer(Yf, 2, 1, 0, 1);    // L3
    layer(Yf, 3, 2, 0, 0);    // L4: no pre-relu
    layer(Yf, 4, 3, 1, 0);    // L5: BN(L4) inline WITH relu

    // L5 BN apply -> XB (bf16), relu
    k_bnb<<<grid1((long long)N * 256 / 4), BS, 0, stream>>>(
        Yf, sums, sumsq, g[4], be[4], XB, N, 256, 1);

    // FC1: XB(bf16 Nx256) @ fcW1 + b, ReLU -> Yf (f32 Nx128)
    gemm(XB, 5, fcb1, Yf, 1);
    // FC2: wave-per-node
    k_fc2w<<<(N * 64 + 255) / 256, 256, 0, stream>>>(Yf, fcW2, fcb2, (float*)d_out, N);
}